// Round 1
// baseline (663.135 us; speedup 1.0000x reference)
//
#include <hip/hip_runtime.h>

// Problem constants (from reference): data (262144, 512) fp32,
// latentZ (1,512) fp32, mu (1,) fp32, tau (1,) fp32.
// Outputs: ir_mu (262144,1) then ir_tau (262144,1), concatenated flat fp32.
#define ROWS 262144
#define LATENT 512

// One wave (64 lanes) per row. Each lane: 2x float4 coalesced loads
// (floats [lane*4, lane*4+3] and [256+lane*4, ...]). latentZ fragment is
// row-invariant -> loaded once into registers. Butterfly shfl reduce.
__global__ __launch_bounds__(256) void linear_svi_kernel(
    const float* __restrict__ data,
    const float* __restrict__ latentZ,
    const float* __restrict__ mu_p,
    const float* __restrict__ tau_p,
    float* __restrict__ out) {
  const int wave = threadIdx.x >> 6;   // 0..3
  const int lane = threadIdx.x & 63;   // 0..63
  const int row = (blockIdx.x << 2) + wave;

  const float mu = mu_p[0];
  const float tau = tau_p[0];

  // latentZ fragment for this lane (same for every row this wave touches)
  const float4* zv = (const float4*)latentZ;
  const float4 z0 = zv[lane];        // floats lane*4 .. lane*4+3
  const float4 z1 = zv[64 + lane];   // floats 256+lane*4 ..

  const float4* xv = (const float4*)(data + (size_t)row * LATENT);
  const float4 x0 = xv[lane];
  const float4 x1 = xv[64 + lane];

  float s = 0.0f;
  float sq = 0.0f;
  float p, d;
#define ACC(zz, xx)                 \
  p = (zz) * (xx);                  \
  s += p;                           \
  d = p - mu;                       \
  sq = fmaf(d, d, sq);
  ACC(z0.x, x0.x) ACC(z0.y, x0.y) ACC(z0.z, x0.z) ACC(z0.w, x0.w)
  ACC(z1.x, x1.x) ACC(z1.y, x1.y) ACC(z1.z, x1.z) ACC(z1.w, x1.w)
#undef ACC

  // 64-lane butterfly reduction of (s, sq)
  #pragma unroll
  for (int off = 32; off > 0; off >>= 1) {
    s += __shfl_xor(s, off, 64);
    sq += __shfl_xor(sq, off, 64);
  }

  if (lane == 0) {
    const float ir_mu = (s + mu) * (1.0f / (1.0f + (float)LATENT));
    const float dm = ir_mu - mu;
    const float ir_tau =
        (tau + 0.5f * (float)LATENT) / (1.0f + 0.5f * sq + dm * dm);
    out[row] = ir_mu;
    out[ROWS + row] = ir_tau;
  }
}

extern "C" void kernel_launch(void* const* d_in, const int* in_sizes, int n_in,
                              void* d_out, int out_size, void* d_ws, size_t ws_size,
                              hipStream_t stream) {
  const float* data    = (const float*)d_in[0];
  const float* latentZ = (const float*)d_in[1];
  const float* mu      = (const float*)d_in[2];
  const float* tau     = (const float*)d_in[3];
  float* out = (float*)d_out;

  // 4 rows per 256-thread block (one wave per row)
  dim3 grid(ROWS / 4);
  dim3 block(256);
  linear_svi_kernel<<<grid, block, 0, stream>>>(data, latentZ, mu, tau, out);
}

// Round 3
// 660.328 us; speedup vs baseline: 1.0043x; 1.0043x over previous
//
#include <hip/hip_runtime.h>

// data (262144, 512) fp32, latentZ (1,512) fp32, mu (1,) fp32, tau (1,) fp32.
// Outputs: ir_mu (262144,) then ir_tau (262144,), concatenated flat fp32.
#define ROWS 262144
#define LATENT 512
#define TPB 256
#define BLOCKS 2048
#define TOTAL_WAVES (BLOCKS * (TPB / 64))      // 8192 waves, 8 per SIMD
#define ROWS_PER_WAVE (ROWS / TOTAL_WAVES)     // 32

// Clang native vector type: accepted by __builtin_nontemporal_load
// (HIP_vector_type float4 is a struct and is rejected).
typedef float vf4 __attribute__((ext_vector_type(4)));

// Persistent-style: each wave owns 32 rows (grid-stride by TOTAL_WAVES).
// Software pipeline: next row's vf4 loads are issued before the current
// row's shuffle-reduction chain so HBM latency overlaps the reduction.
__global__ __launch_bounds__(TPB) void linear_svi_kernel(
    const float* __restrict__ data,
    const float* __restrict__ latentZ,
    const float* __restrict__ mu_p,
    const float* __restrict__ tau_p,
    float* __restrict__ out) {
  const int lane = threadIdx.x & 63;
  const int wave_g = (blockIdx.x << 2) + (threadIdx.x >> 6);  // 0..8191

  const float mu = mu_p[0];
  const float tau = tau_p[0];

  // latentZ fragment: row-invariant, loaded once, L1/L2-resident.
  const vf4* zv = (const vf4*)latentZ;
  const vf4 z0 = zv[lane];
  const vf4 z1 = zv[64 + lane];

  int row = wave_g;
  const vf4* p = (const vf4*)(data + (size_t)row * LATENT);
  vf4 x0 = __builtin_nontemporal_load(p + lane);
  vf4 x1 = __builtin_nontemporal_load(p + 64 + lane);

  for (int k = 0; k < ROWS_PER_WAVE; ++k) {
    // Prefetch next row before touching x0/x1's dependents.
    vf4 nx0, nx1;
    const int nrow = row + TOTAL_WAVES;
    if (k + 1 < ROWS_PER_WAVE) {
      const vf4* np = (const vf4*)(data + (size_t)nrow * LATENT);
      nx0 = __builtin_nontemporal_load(np + lane);
      nx1 = __builtin_nontemporal_load(np + 64 + lane);
    }

    float s = 0.0f, sq = 0.0f, prod, dd;
#define ACC(zz, xx)            \
    prod = (zz) * (xx);        \
    s += prod;                 \
    dd = prod - mu;            \
    sq = fmaf(dd, dd, sq);
    ACC(z0.x, x0.x) ACC(z0.y, x0.y) ACC(z0.z, x0.z) ACC(z0.w, x0.w)
    ACC(z1.x, x1.x) ACC(z1.y, x1.y) ACC(z1.z, x1.z) ACC(z1.w, x1.w)
#undef ACC

    // 64-lane butterfly; s/sq chains are independent and interleave.
#pragma unroll
    for (int off = 32; off > 0; off >>= 1) {
      s += __shfl_xor(s, off, 64);
      sq += __shfl_xor(sq, off, 64);
    }

    // Every lane has the totals; lanes 0 and 1 store ir_mu / ir_tau
    // in a single store instruction (2 active lanes).
    if (lane < 2) {
      const float ir_mu = (s + mu) * (1.0f / 513.0f);
      const float dm = ir_mu - mu;
      const float ir_tau = (tau + 256.0f) / (1.0f + 0.5f * sq + dm * dm);
      const float v = lane ? ir_tau : ir_mu;
      out[(size_t)lane * ROWS + row] = v;
    }

    x0 = nx0;
    x1 = nx1;
    row = nrow;
  }
}

extern "C" void kernel_launch(void* const* d_in, const int* in_sizes, int n_in,
                              void* d_out, int out_size, void* d_ws, size_t ws_size,
                              hipStream_t stream) {
  const float* data    = (const float*)d_in[0];
  const float* latentZ = (const float*)d_in[1];
  const float* mu      = (const float*)d_in[2];
  const float* tau     = (const float*)d_in[3];
  float* out = (float*)d_out;

  linear_svi_kernel<<<dim3(BLOCKS), dim3(TPB), 0, stream>>>(data, latentZ, mu,
                                                            tau, out);
}